// Round 1
// baseline (359.513 us; speedup 1.0000x reference)
//
#include <hip/hip_runtime.h>

// MHA forward, MI355X gfx950.
// Sizes: B=4, S=2048, DIN=EMB=1024, H=16, D(head)=64.
// Stage 1: QKV projection GEMM (bf16 MFMA, fp32 accum), writes bf16 Q/K/V to ws
//          in [b,h,s,d] layout (48 MB of d_ws).
// Stage 2: causal flash attention; computes S^T = K·Q^T (swapped operands) so
//          softmax is lane-local per q-column, and O^T = V^T·P^T so the
//          reference's transposed output layout out[b][h*64*2048 + d*2048 + s]
//          is stored coalesced along s.

#define BSZ 4
#define SLEN 2048
#define DIN 1024
#define EMB 1024
#define HNO 16
#define HSZ 64

typedef unsigned short u16;
typedef __bf16 bf16x8_t __attribute__((ext_vector_type(8)));
typedef float f32x4_t __attribute__((ext_vector_type(4)));

__device__ __forceinline__ u16 f2bf(float f) {
    unsigned u = __float_as_uint(f);
    u += 0x7FFFu + ((u >> 16) & 1u);   // RNE; inputs are finite
    return (u16)(u >> 16);
}

// ---------------------------------------------------------------------------
// Kernel A: Y = x @ W^T + b for W in {Wq,Wk,Wv}, output bf16 scattered to
// [b,h,s,d]. Tile 128x128, BK=32, 4 waves (2x2), each wave 64x64 via 4x4
// mfma_f32_16x16x32_bf16 fragments.
// grid = (M/128 = 64, 3*1024/128 = 24), block = 256.
// ---------------------------------------------------------------------------
__global__ __launch_bounds__(256) void qkv_proj_kernel(
    const float* __restrict__ x,
    const float* __restrict__ Wq, const float* __restrict__ bq,
    const float* __restrict__ Wk, const float* __restrict__ bk,
    const float* __restrict__ Wv, const float* __restrict__ bv,
    u16* __restrict__ qo, u16* __restrict__ ko, u16* __restrict__ vo)
{
    // pad 40 elems (80 B row stride): ds_read_b128 lands 2-way = free (m136)
    __shared__ __attribute__((aligned(16))) u16 As[128][40];
    __shared__ __attribute__((aligned(16))) u16 Bs[128][40];

    const int t    = threadIdx.x;
    const int wid  = t >> 6;
    const int lane = t & 63;
    const int g    = lane >> 4;    // 4 lane-groups
    const int r16  = lane & 15;

    const int m0  = blockIdx.x * 128;
    const int ng  = blockIdx.y * 128;
    const int mat = ng >> 10;          // 0=Q 1=K 2=V
    const int n0  = ng & 1023;

    const float* W    = (mat == 0) ? Wq : (mat == 1) ? Wk : Wv;
    const float* bias = (mat == 0) ? bq : (mat == 1) ? bk : bv;
    u16*         outp = (mat == 0) ? qo : (mat == 1) ? ko : vo;

    const int wm = wid >> 1, wn = wid & 1;

    f32x4_t acc[4][4] = {};

    for (int k0 = 0; k0 < DIN; k0 += 32) {
        __syncthreads();
        // stage: 128x32 fp32 -> bf16 LDS, for both A (x) and B (W)
#pragma unroll
        for (int i = 0; i < 4; ++i) {
            int idx = i * 256 + t;
            int row = idx >> 3;
            int c4  = (idx & 7) * 4;
            float4 a = *reinterpret_cast<const float4*>(&x[(size_t)(m0 + row) * DIN + k0 + c4]);
            float4 b = *reinterpret_cast<const float4*>(&W[(size_t)(n0 + row) * DIN + k0 + c4]);
            unsigned long long pa =
                (unsigned long long)f2bf(a.x) | ((unsigned long long)f2bf(a.y) << 16) |
                ((unsigned long long)f2bf(a.z) << 32) | ((unsigned long long)f2bf(a.w) << 48);
            unsigned long long pb =
                (unsigned long long)f2bf(b.x) | ((unsigned long long)f2bf(b.y) << 16) |
                ((unsigned long long)f2bf(b.z) << 32) | ((unsigned long long)f2bf(b.w) << 48);
            *reinterpret_cast<unsigned long long*>(&As[row][c4]) = pa;
            *reinterpret_cast<unsigned long long*>(&Bs[row][c4]) = pb;
        }
        __syncthreads();

        bf16x8_t af[4], bfv[4];
#pragma unroll
        for (int i = 0; i < 4; ++i)
            af[i] = *reinterpret_cast<const bf16x8_t*>(&As[wm * 64 + i * 16 + r16][g * 8]);
#pragma unroll
        for (int j = 0; j < 4; ++j)
            bfv[j] = *reinterpret_cast<const bf16x8_t*>(&Bs[wn * 64 + j * 16 + r16][g * 8]);
#pragma unroll
        for (int i = 0; i < 4; ++i)
#pragma unroll
            for (int j = 0; j < 4; ++j)
                acc[i][j] = __builtin_amdgcn_mfma_f32_16x16x32_bf16(af[i], bfv[j], acc[i][j], 0, 0, 0);
    }

    // epilogue: +bias, bf16, scatter to [b,h,s,d]
#pragma unroll
    for (int j = 0; j < 4; ++j) {
        int e = n0 + wn * 64 + j * 16 + r16;      // C col = lane&15
        float bv_ = bias[e];
        int h = e >> 6, d = e & 63;
#pragma unroll
        for (int i = 0; i < 4; ++i) {
#pragma unroll
            for (int r = 0; r < 4; ++r) {
                int m = m0 + wm * 64 + i * 16 + g * 4 + r;   // C row = (lane>>4)*4+reg
                int b = m >> 11, s = m & 2047;
                float val = acc[i][j][r] + bv_;
                outp[(((size_t)(b * HNO + h)) * SLEN + s) * HSZ + d] = f2bf(val);
            }
        }
    }
}

// ---------------------------------------------------------------------------
// Kernel B: causal flash attention. Block = 4 waves, each wave owns 16 q rows
// (BQ=64). KV tiles of 32. Computes S^T (= K·Q^T) so each lane holds 8 score
// values for ONE q-column (softmax: in-lane + shfl_xor 16/32), then
// O^T = V^T·P^T so the output store along s is coalesced.
// grid = (S/64 = 32, B*H = 64), block = 256.
// ---------------------------------------------------------------------------
__global__ __launch_bounds__(256) void attn_kernel(
    const u16* __restrict__ qb, const u16* __restrict__ kb,
    const u16* __restrict__ vb, float* __restrict__ out)
{
    __shared__ __attribute__((aligned(16))) u16 Ks[32][72];     // K tile, row-major, pad 72
    __shared__ __attribute__((aligned(16))) u16 Vt[64][40];     // V^T tile [d][kv], pad 40
    __shared__ __attribute__((aligned(16))) u16 P2[4][16][40];  // per-wave P[q][kv], pad 40

    const int t    = threadIdx.x;
    const int wid  = t >> 6;
    const int lane = t & 63;
    const int g    = lane >> 4;
    const int r16  = lane & 15;

    const int qt = blockIdx.x;
    const int bh = blockIdx.y;
    const int q0 = qt * 64;
    const size_t base = (size_t)bh * SLEN * HSZ;

    // Q B-fragment: col q = r16, k = d = g*8 + j (+32 for second chunk)
    const int qi = q0 + wid * 16 + r16;  // this lane's q column (global row index)
    bf16x8_t qf0 = *reinterpret_cast<const bf16x8_t*>(&qb[base + (size_t)qi * HSZ + g * 8]);
    bf16x8_t qf1 = *reinterpret_cast<const bf16x8_t*>(&qb[base + (size_t)qi * HSZ + 32 + g * 8]);

    f32x4_t o[4] = {};                  // O^T accum: row d = j*16 + 4g + r, col q = r16
    float mrow = -1e30f, lrow = 0.f;

    const int qmax_wave = q0 + wid * 16 + 15;
    const int ntiles = (q0 + 64) >> 5;  // causal: kv0 < q0+64

    for (int kt = 0; kt < ntiles; ++kt) {
        const int kv0 = kt * 32;
        __syncthreads();
        {   // stage K [32][64] row-major + V^T [64][32]
            int row = t >> 3, c0 = (t & 7) * 8;
            uint4 k4 = *reinterpret_cast<const uint4*>(&kb[base + (size_t)(kv0 + row) * HSZ + c0]);
            *reinterpret_cast<uint4*>(&Ks[row][c0]) = k4;
            uint4 v4 = *reinterpret_cast<const uint4*>(&vb[base + (size_t)(kv0 + row) * HSZ + c0]);
            unsigned wv_[4] = {v4.x, v4.y, v4.z, v4.w};
#pragma unroll
            for (int j2 = 0; j2 < 4; ++j2) {
                Vt[c0 + 2 * j2][row]     = (u16)(wv_[j2] & 0xffffu);
                Vt[c0 + 2 * j2 + 1][row] = (u16)(wv_[j2] >> 16);
            }
        }
        __syncthreads();

        if (kv0 <= qmax_wave) {
            // S^T = K·Q^T : A = K (row kv = lane&15 per half, k = d), B = Q
            bf16x8_t k00 = *reinterpret_cast<const bf16x8_t*>(&Ks[r16][g * 8]);
            bf16x8_t k01 = *reinterpret_cast<const bf16x8_t*>(&Ks[r16][32 + g * 8]);
            bf16x8_t k10 = *reinterpret_cast<const bf16x8_t*>(&Ks[16 + r16][g * 8]);
            bf16x8_t k11 = *reinterpret_cast<const bf16x8_t*>(&Ks[16 + r16][32 + g * 8]);
            f32x4_t c0v = {}, c1v = {};
            c0v = __builtin_amdgcn_mfma_f32_16x16x32_bf16(k00, qf0, c0v, 0, 0, 0);
            c0v = __builtin_amdgcn_mfma_f32_16x16x32_bf16(k01, qf1, c0v, 0, 0, 0);
            c1v = __builtin_amdgcn_mfma_f32_16x16x32_bf16(k10, qf0, c1v, 0, 0, 0);
            c1v = __builtin_amdgcn_mfma_f32_16x16x32_bf16(k11, qf1, c1v, 0, 0, 0);

            // lane holds S^T[kv = kv0 + {0,16} + 4g + r][q = qi]
            float s0[4], s1[4];
            float tmax = -1e30f;
#pragma unroll
            for (int r = 0; r < 4; ++r) {
                int kj0 = kv0 + g * 4 + r;
                int kj1 = kj0 + 16;
                s0[r] = (kj0 <= qi) ? c0v[r] * 0.125f : -1e30f;
                s1[r] = (kj1 <= qi) ? c1v[r] * 0.125f : -1e30f;
                tmax = fmaxf(tmax, fmaxf(s0[r], s1[r]));
            }
            tmax = fmaxf(tmax, __shfl_xor(tmax, 16));
            tmax = fmaxf(tmax, __shfl_xor(tmax, 32));
            float mnew  = fmaxf(mrow, tmax);
            float alpha = __expf(mrow - mnew);
            float tsum = 0.f;
            float p0[4], p1[4];
#pragma unroll
            for (int r = 0; r < 4; ++r) {
                p0[r] = __expf(s0[r] - mnew);
                p1[r] = __expf(s1[r] - mnew);
                tsum += p0[r] + p1[r];
            }
            tsum += __shfl_xor(tsum, 16);
            tsum += __shfl_xor(tsum, 32);
            lrow = lrow * alpha + tsum;
            mrow = mnew;
#pragma unroll
            for (int j = 0; j < 4; ++j) {
                o[j][0] *= alpha; o[j][1] *= alpha; o[j][2] *= alpha; o[j][3] *= alpha;
            }
            // P^T (C-layout) -> P2[q][kv] so the PV B-frag read is contiguous
#pragma unroll
            for (int r = 0; r < 4; ++r) {
                P2[wid][r16][g * 4 + r]      = f2bf(p0[r]);
                P2[wid][r16][16 + g * 4 + r] = f2bf(p1[r]);
            }
            // O^T += V^T · P^T  (A = V^T: row d = lane&15, k = kv; B = P^T)
            bf16x8_t pf = *reinterpret_cast<const bf16x8_t*>(&P2[wid][r16][g * 8]);
#pragma unroll
            for (int j = 0; j < 4; ++j) {
                bf16x8_t vf = *reinterpret_cast<const bf16x8_t*>(&Vt[j * 16 + r16][g * 8]);
                o[j] = __builtin_amdgcn_mfma_f32_16x16x32_bf16(vf, pf, o[j], 0, 0, 0);
            }
        }
    }

    // normalize + store: out[b][h*64*2048 + d*2048 + s], coalesced along s
    float rinv = 1.0f / lrow;
    const int b = bh >> 4, h = bh & 15;
    float* outb = out + (size_t)b * (SLEN * EMB) + (size_t)h * (HSZ * SLEN);
#pragma unroll
    for (int j = 0; j < 4; ++j) {
#pragma unroll
        for (int r = 0; r < 4; ++r) {
            int d = j * 16 + g * 4 + r;
            outb[(size_t)d * SLEN + qi] = o[j][r] * rinv;
        }
    }
}

// ---------------------------------------------------------------------------
extern "C" void kernel_launch(void* const* d_in, const int* in_sizes, int n_in,
                              void* d_out, int out_size, void* d_ws, size_t ws_size,
                              hipStream_t stream) {
    const float* x  = (const float*)d_in[0];
    const float* Wq = (const float*)d_in[1];
    const float* bq = (const float*)d_in[2];
    const float* Wk = (const float*)d_in[3];
    const float* bk = (const float*)d_in[4];
    const float* Wv = (const float*)d_in[5];
    const float* bv = (const float*)d_in[6];
    float* out = (float*)d_out;

    const size_t per = (size_t)BSZ * HNO * SLEN * HSZ;  // 8,388,608 elems
    u16* qw = (u16*)d_ws;          // needs 3*per*2 = 48 MB of workspace
    u16* kw = qw + per;
    u16* vw = kw + per;

    qkv_proj_kernel<<<dim3(64, 24), 256, 0, stream>>>(x, Wq, bq, Wk, bk, Wv, bv, qw, kw, vw);
    attn_kernel<<<dim3(SLEN / 64, BSZ * HNO), 256, 0, stream>>>(qw, kw, vw, out);
}

// Round 2
// 182.004 us; speedup vs baseline: 1.9753x; 1.9753x over previous
//
#include <hip/hip_runtime.h>

// MHA forward, MI355X gfx950.
// Sizes: B=4, S=2048, DIN=EMB=1024, H=16, D(head)=64.
// Stage 1: QKV projection GEMM (bf16 MFMA, fp32 accum), writes bf16 Q/K/V to ws
//          in [b,h,s,d] layout. Q is pre-scaled by 1/sqrt(64).
// Stage 2: causal flash attention, KVBLK=64, async-staged (regs->LDS),
//          bank-conflict-free layouts, XCD-head-affine block swizzle,
//          reversed qt order (big causal blocks first), defer-max rescale.

#define BSZ 4
#define SLEN 2048
#define DIN 1024
#define EMB 1024
#define HNO 16
#define HSZ 64

typedef unsigned short u16;
typedef __bf16 bf16x8_t __attribute__((ext_vector_type(8)));
typedef float f32x4_t __attribute__((ext_vector_type(4)));

__device__ __forceinline__ u16 f2bf(float f) {
    unsigned u = __float_as_uint(f);
    u += 0x7FFFu + ((u >> 16) & 1u);   // RNE; inputs are finite
    return (u16)(u >> 16);
}

// ---------------------------------------------------------------------------
// Kernel A: Y = x @ W^T + b for W in {Wq,Wk,Wv}, output bf16 scattered to
// [b,h,s,d]. Tile 128x128, BK=32, 4 waves (2x2), each wave 64x64 via 4x4
// mfma_f32_16x16x32_bf16 fragments. Q output is scaled by 0.125 (1/sqrt(hd)).
// grid = (64, 24), block = 256.
// ---------------------------------------------------------------------------
__global__ __launch_bounds__(256) void qkv_proj_kernel(
    const float* __restrict__ x,
    const float* __restrict__ Wq, const float* __restrict__ bq,
    const float* __restrict__ Wk, const float* __restrict__ bk,
    const float* __restrict__ Wv, const float* __restrict__ bv,
    u16* __restrict__ qo, u16* __restrict__ ko, u16* __restrict__ vo)
{
    __shared__ __attribute__((aligned(16))) u16 As[128][40];
    __shared__ __attribute__((aligned(16))) u16 Bs[128][40];

    const int t    = threadIdx.x;
    const int wid  = t >> 6;
    const int lane = t & 63;
    const int g    = lane >> 4;
    const int r16  = lane & 15;

    const int m0  = blockIdx.x * 128;
    const int ng  = blockIdx.y * 128;
    const int mat = ng >> 10;          // 0=Q 1=K 2=V
    const int n0  = ng & 1023;

    const float* W    = (mat == 0) ? Wq : (mat == 1) ? Wk : Wv;
    const float* bias = (mat == 0) ? bq : (mat == 1) ? bk : bv;
    u16*         outp = (mat == 0) ? qo : (mat == 1) ? ko : vo;
    const float  qs   = (mat == 0) ? 0.125f : 1.0f;

    const int wm = wid >> 1, wn = wid & 1;

    f32x4_t acc[4][4] = {};

    for (int k0 = 0; k0 < DIN; k0 += 32) {
        __syncthreads();
#pragma unroll
        for (int i = 0; i < 4; ++i) {
            int idx = i * 256 + t;
            int row = idx >> 3;
            int c4  = (idx & 7) * 4;
            float4 a = *reinterpret_cast<const float4*>(&x[(size_t)(m0 + row) * DIN + k0 + c4]);
            float4 b = *reinterpret_cast<const float4*>(&W[(size_t)(n0 + row) * DIN + k0 + c4]);
            unsigned long long pa =
                (unsigned long long)f2bf(a.x) | ((unsigned long long)f2bf(a.y) << 16) |
                ((unsigned long long)f2bf(a.z) << 32) | ((unsigned long long)f2bf(a.w) << 48);
            unsigned long long pb =
                (unsigned long long)f2bf(b.x) | ((unsigned long long)f2bf(b.y) << 16) |
                ((unsigned long long)f2bf(b.z) << 32) | ((unsigned long long)f2bf(b.w) << 48);
            *reinterpret_cast<unsigned long long*>(&As[row][c4]) = pa;
            *reinterpret_cast<unsigned long long*>(&Bs[row][c4]) = pb;
        }
        __syncthreads();

        bf16x8_t af[4], bfv[4];
#pragma unroll
        for (int i = 0; i < 4; ++i)
            af[i] = *reinterpret_cast<const bf16x8_t*>(&As[wm * 64 + i * 16 + r16][g * 8]);
#pragma unroll
        for (int j = 0; j < 4; ++j)
            bfv[j] = *reinterpret_cast<const bf16x8_t*>(&Bs[wn * 64 + j * 16 + r16][g * 8]);
#pragma unroll
        for (int i = 0; i < 4; ++i)
#pragma unroll
            for (int j = 0; j < 4; ++j)
                acc[i][j] = __builtin_amdgcn_mfma_f32_16x16x32_bf16(af[i], bfv[j], acc[i][j], 0, 0, 0);
    }

#pragma unroll
    for (int j = 0; j < 4; ++j) {
        int e = n0 + wn * 64 + j * 16 + r16;
        float bv_ = bias[e];
        int h = e >> 6, d = e & 63;
#pragma unroll
        for (int i = 0; i < 4; ++i) {
#pragma unroll
            for (int r = 0; r < 4; ++r) {
                int m = m0 + wm * 64 + i * 16 + g * 4 + r;
                int b = m >> 11, s = m & 2047;
                float val = (acc[i][j][r] + bv_) * qs;
                outp[(((size_t)(b * HNO + h)) * SLEN + s) * HSZ + d] = f2bf(val);
            }
        }
    }
}

// ---------------------------------------------------------------------------
// Kernel B: causal flash attention. Block = 4 waves, BQ=64 (16 q/wave),
// KVBLK=64. S^T = K·Q^T (lane owns one q-column -> lane-local softmax with
// shfl_xor 16/32 reduce), O^T = V^T·P^T (coalesced output stores along s).
// Async staging: next tile's K/V in regs while computing current tile.
// grid = 2048 (1D, swizzled), block = 256.
// ---------------------------------------------------------------------------
__global__ __launch_bounds__(256) void attn_kernel(
    const u16* __restrict__ qb, const u16* __restrict__ kb,
    const u16* __restrict__ vb, float* __restrict__ out)
{
    // stride 72 u16 = 36 dwords: b128 reads spread 8 lanes per 4-bank group
    __shared__ __attribute__((aligned(16))) u16 Ks[64][72];     // K tile [kv][d]
    __shared__ __attribute__((aligned(16))) u16 Vt[64][72];     // V^T tile [d][kv]
    __shared__ __attribute__((aligned(16))) u16 P2[4][16][72];  // per-wave P[q][kv]

    const int t    = threadIdx.x;
    const int wid  = t >> 6;
    const int lane = t & 63;
    const int g    = lane >> 4;
    const int r16  = lane & 15;

    // swizzle: xcd = w&7 pins 8 heads per XCD (4 MB K/V = one L2);
    // qt descending so the biggest causal blocks launch first.
    const int w   = blockIdx.x;
    const int idx = w >> 3;
    const int bh  = (w & 7) * 8 + (idx & 7);
    const int qt  = 31 - (idx >> 3);
    const int q0  = qt * 64;
    const size_t base = (size_t)bh * (SLEN * HSZ);

    const int qi = q0 + wid * 16 + r16;     // this lane's q column
    bf16x8_t qf0 = *reinterpret_cast<const bf16x8_t*>(&qb[base + (size_t)qi * HSZ + g * 8]);
    bf16x8_t qf1 = *reinterpret_cast<const bf16x8_t*>(&qb[base + (size_t)qi * HSZ + 32 + g * 8]);

    // staging thread->element maps
    const int krow = t >> 3, kc0 = (t & 7) * 8;     // K: rows krow, krow+32
    const int vrp  = t & 31, vc0 = (t >> 5) * 8;    // V: rows 2vrp, 2vrp+1

    f32x4_t o[4] = {};
    float mrow = -1e30f, lrow = 0.f;

    const int ntiles = qt + 1;

    // preload tile 0 into regs
    uint4 kA = *reinterpret_cast<const uint4*>(&kb[base + (size_t)krow * HSZ + kc0]);
    uint4 kB = *reinterpret_cast<const uint4*>(&kb[base + (size_t)(krow + 32) * HSZ + kc0]);
    uint4 vA = *reinterpret_cast<const uint4*>(&vb[base + (size_t)(2 * vrp) * HSZ + vc0]);
    uint4 vB = *reinterpret_cast<const uint4*>(&vb[base + (size_t)(2 * vrp + 1) * HSZ + vc0]);

    for (int kt = 0; kt < ntiles; ++kt) {
        const int kv0 = kt * 64;
        __syncthreads();                    // prev tile's LDS consumers done
        // regs -> LDS (vmcnt wait auto-inserted)
        *reinterpret_cast<uint4*>(&Ks[krow][kc0])      = kA;
        *reinterpret_cast<uint4*>(&Ks[krow + 32][kc0]) = kB;
        {
            const u16* p0 = reinterpret_cast<const u16*>(&vA);
            const u16* p1 = reinterpret_cast<const u16*>(&vB);
#pragma unroll
            for (int j = 0; j < 8; ++j) {   // transpose-write: 32 banks, 2 lanes each
                unsigned pk = (unsigned)p0[j] | ((unsigned)p1[j] << 16);
                *reinterpret_cast<unsigned*>(&Vt[vc0 + j][2 * vrp]) = pk;
            }
        }
        __syncthreads();

        if (kt + 1 < ntiles) {              // async prefetch next tile
            const size_t nb = base + (size_t)(kv0 + 64) * HSZ;
            kA = *reinterpret_cast<const uint4*>(&kb[nb + (size_t)krow * HSZ + kc0]);
            kB = *reinterpret_cast<const uint4*>(&kb[nb + (size_t)(krow + 32) * HSZ + kc0]);
            vA = *reinterpret_cast<const uint4*>(&vb[nb + (size_t)(2 * vrp) * HSZ + vc0]);
            vB = *reinterpret_cast<const uint4*>(&vb[nb + (size_t)(2 * vrp + 1) * HSZ + vc0]);
        }

        // S^T = K·Q^T : 4 kv-frags x 2 k-chunks (Q pre-scaled by 1/8)
        f32x4_t c_[4];
#pragma unroll
        for (int m = 0; m < 4; ++m) {
            bf16x8_t a0 = *reinterpret_cast<const bf16x8_t*>(&Ks[m * 16 + r16][g * 8]);
            bf16x8_t a1 = *reinterpret_cast<const bf16x8_t*>(&Ks[m * 16 + r16][32 + g * 8]);
            f32x4_t cc = {};
            cc = __builtin_amdgcn_mfma_f32_16x16x32_bf16(a0, qf0, cc, 0, 0, 0);
            cc = __builtin_amdgcn_mfma_f32_16x16x32_bf16(a1, qf1, cc, 0, 0, 0);
            c_[m] = cc;
        }

        // softmax (lane owns q=qi; kv = kv0 + 16m + 4g + r)
        float s[16];
        float tmax = -1e30f;
        if (kt == qt) {                     // diagonal tile: causal mask
#pragma unroll
            for (int m = 0; m < 4; ++m)
#pragma unroll
                for (int r = 0; r < 4; ++r) {
                    int kj = kv0 + m * 16 + g * 4 + r;
                    float v = (kj <= qi) ? c_[m][r] : -1e30f;
                    s[m * 4 + r] = v;
                    tmax = fmaxf(tmax, v);
                }
        } else {
#pragma unroll
            for (int m = 0; m < 4; ++m)
#pragma unroll
                for (int r = 0; r < 4; ++r) {
                    float v = c_[m][r];
                    s[m * 4 + r] = v;
                    tmax = fmaxf(tmax, v);
                }
        }
        tmax = fmaxf(tmax, __shfl_xor(tmax, 16));
        tmax = fmaxf(tmax, __shfl_xor(tmax, 32));

        if (!__all(tmax - mrow <= 8.0f)) {  // defer-max: skip rescale if bounded
            float mnew  = fmaxf(mrow, tmax);
            float alpha = __expf(mrow - mnew);
#pragma unroll
            for (int j = 0; j < 4; ++j) {
                o[j][0] *= alpha; o[j][1] *= alpha; o[j][2] *= alpha; o[j][3] *= alpha;
            }
            lrow *= alpha;
            mrow = mnew;
        }

        float p[16];
        float tsum = 0.f;
#pragma unroll
        for (int i = 0; i < 16; ++i) {
            p[i] = __expf(s[i] - mrow);
            tsum += p[i];
        }
        tsum += __shfl_xor(tsum, 16);
        tsum += __shfl_xor(tsum, 32);
        lrow += tsum;

        // P^T -> per-wave LDS (packed b64 writes)
#pragma unroll
        for (int m = 0; m < 4; ++m) {
            unsigned long long pk =
                (unsigned long long)f2bf(p[m * 4 + 0])        |
                ((unsigned long long)f2bf(p[m * 4 + 1]) << 16) |
                ((unsigned long long)f2bf(p[m * 4 + 2]) << 32) |
                ((unsigned long long)f2bf(p[m * 4 + 3]) << 48);
            *reinterpret_cast<unsigned long long*>(&P2[wid][r16][m * 16 + g * 4]) = pk;
        }

        // O^T += V^T·P^T : 4 d-frags x 2 kv-chunks
#pragma unroll
        for (int c = 0; c < 2; ++c) {
            bf16x8_t pf = *reinterpret_cast<const bf16x8_t*>(&P2[wid][r16][c * 32 + g * 8]);
#pragma unroll
            for (int j = 0; j < 4; ++j) {
                bf16x8_t vf = *reinterpret_cast<const bf16x8_t*>(&Vt[j * 16 + r16][c * 32 + g * 8]);
                o[j] = __builtin_amdgcn_mfma_f32_16x16x32_bf16(vf, pf, o[j], 0, 0, 0);
            }
        }
    }

    // normalize + store: out[b][h*64*2048 + d*2048 + s], coalesced along s
    float rinv = 1.0f / lrow;
    const int b = bh >> 4, h = bh & 15;
    float* outb = out + (size_t)b * (SLEN * EMB) + (size_t)h * (HSZ * SLEN);
#pragma unroll
    for (int j = 0; j < 4; ++j) {
#pragma unroll
        for (int r = 0; r < 4; ++r) {
            int d = j * 16 + g * 4 + r;
            outb[(size_t)d * SLEN + qi] = o[j][r] * rinv;
        }
    }
}

// ---------------------------------------------------------------------------
extern "C" void kernel_launch(void* const* d_in, const int* in_sizes, int n_in,
                              void* d_out, int out_size, void* d_ws, size_t ws_size,
                              hipStream_t stream) {
    const float* x  = (const float*)d_in[0];
    const float* Wq = (const float*)d_in[1];
    const float* bq = (const float*)d_in[2];
    const float* Wk = (const float*)d_in[3];
    const float* bk = (const float*)d_in[4];
    const float* Wv = (const float*)d_in[5];
    const float* bv = (const float*)d_in[6];
    float* out = (float*)d_out;

    const size_t per = (size_t)BSZ * HNO * SLEN * HSZ;
    u16* qw = (u16*)d_ws;          // 3*per*2 = 48 MB of workspace
    u16* kw = qw + per;
    u16* vw = kw + per;

    qkv_proj_kernel<<<dim3(64, 24), 256, 0, stream>>>(x, Wq, bq, Wk, bk, Wv, bv, qw, kw, vw);
    attn_kernel<<<2048, 256, 0, stream>>>(qw, kw, vw, out);
}

// Round 3
// 153.105 us; speedup vs baseline: 2.3481x; 1.1887x over previous
//
#include <hip/hip_runtime.h>

// MHA forward, MI355X gfx950.
// Sizes: B=4, S=2048, DIN=EMB=1024, H=16, D(head)=64.
// Stage 0: one-shot fp32->bf16 convert of x and Wq/Wk/Wv (memory-bound),
//          bf16 copies live in d_out (used as scratch; attn overwrites it).
// Stage 1: pure-bf16 QKV GEMM, m97 structure: 128x128 tile, BK=32,
//          global_load_lds width-16, 2-barrier K-loop. Writes bf16 Q/K/V
//          to d_ws in [b,h,s,d] layout; Q pre-scaled by 1/sqrt(64).
// Stage 2: causal flash attention, KVBLK=64, reg->LDS async staging,
//          conflict-free layouts, XCD-head-affine swizzle, defer-max.

#define BSZ 4
#define SLEN 2048
#define DIN 1024
#define EMB 1024
#define HNO 16
#define HSZ 64

typedef unsigned short u16;
typedef __bf16 bf16x8_t __attribute__((ext_vector_type(8)));
typedef float f32x4_t __attribute__((ext_vector_type(4)));

__device__ __forceinline__ u16 f2bf(float f) {
    unsigned u = __float_as_uint(f);
    u += 0x7FFFu + ((u >> 16) & 1u);   // RNE; inputs are finite
    return (u16)(u >> 16);
}

__device__ __forceinline__ void gld16(void* lds, const void* g) {
    __builtin_amdgcn_global_load_lds(
        (const __attribute__((address_space(1))) void*)g,
        (__attribute__((address_space(3))) void*)lds, 16, 0, 0);
}

// ---------------------------------------------------------------------------
// Stage 0: fp32 -> bf16, vectorized (32B in / 16B out per lane per iter).
// blockIdx.y: 0 = x, 1..3 = Wq/Wk/Wv (into contiguous wb).
// ---------------------------------------------------------------------------
__global__ __launch_bounds__(256) void cvt_bf16_kernel(
    const float* __restrict__ x,  const float* __restrict__ wq,
    const float* __restrict__ wk, const float* __restrict__ wv,
    u16* __restrict__ xo, u16* __restrict__ wo)
{
    const int y = blockIdx.y;
    const float* src = (y == 0) ? x : (y == 1) ? wq : (y == 2) ? wk : wv;
    u16* dst = (y == 0) ? xo : wo + (size_t)(y - 1) * (EMB * DIN);
    const int n8 = (y == 0) ? (BSZ * SLEN * DIN / 8) : (EMB * DIN / 8);

    for (int i = blockIdx.x * 256 + threadIdx.x; i < n8; i += gridDim.x * 256) {
        float4 a = *reinterpret_cast<const float4*>(src + (size_t)i * 8);
        float4 b = *reinterpret_cast<const float4*>(src + (size_t)i * 8 + 4);
        union { u16 h[8]; uint4 u; } p;
        p.h[0] = f2bf(a.x); p.h[1] = f2bf(a.y); p.h[2] = f2bf(a.z); p.h[3] = f2bf(a.w);
        p.h[4] = f2bf(b.x); p.h[5] = f2bf(b.y); p.h[6] = f2bf(b.z); p.h[7] = f2bf(b.w);
        *reinterpret_cast<uint4*>(dst + (size_t)i * 8) = p.u;
    }
}

// ---------------------------------------------------------------------------
// Stage 1: Y = xb @ W^T + b, all bf16 inputs. m97 structure: 128x128 tile,
// BK=32, 4 waves (2x2), 4x4 16x16x32 frags/wave, global_load_lds staging.
// grid = (64 Mtiles, 8 Ntiles, 3 matrices), block = 256.
// ---------------------------------------------------------------------------
__global__ __launch_bounds__(256) void qkv_gemm_kernel(
    const u16* __restrict__ xb, const u16* __restrict__ wb,
    const float* __restrict__ bq, const float* __restrict__ bk,
    const float* __restrict__ bv,
    u16* __restrict__ qo, u16* __restrict__ ko, u16* __restrict__ vo)
{
    __shared__ __attribute__((aligned(16))) u16 As[128][32];  // linear: gld dest
    __shared__ __attribute__((aligned(16))) u16 Bs[128][32];

    const int t    = threadIdx.x;
    const int wid  = t >> 6;
    const int lane = t & 63;
    const int g    = lane >> 4;
    const int r16  = lane & 15;

    const int m0  = blockIdx.x * 128;
    const int n0  = blockIdx.y * 128;
    const int mat = blockIdx.z;

    const u16*   W    = wb + (size_t)mat * (EMB * DIN);
    const float* bias = (mat == 0) ? bq : (mat == 1) ? bk : bv;
    u16*         outp = (mat == 0) ? qo : (mat == 1) ? ko : vo;
    const float  qs   = (mat == 0) ? 0.125f : 1.0f;

    const int wm = wid >> 1, wn = wid & 1;

    // staging map: lane l covers row wid*16 + (l>>2) (+64 for issue 1),
    // elems (l&3)*8 .. +8. LDS dest is wave-uniform base + lane*16 (linear).
    const int srow = lane >> 2;
    const int scol = (lane & 3) * 8;
    const u16* gA = xb + (size_t)(m0 + wid * 16 + srow) * DIN + scol;
    const u16* gB = W  + (size_t)(n0 + wid * 16 + srow) * DIN + scol;
    u16* lA0 = &As[wid * 16][0];
    u16* lA1 = &As[64 + wid * 16][0];
    u16* lB0 = &Bs[wid * 16][0];
    u16* lB1 = &Bs[64 + wid * 16][0];

    f32x4_t acc[4][4] = {};

    for (int k0 = 0; k0 < DIN; k0 += 32) {
        __syncthreads();                       // prior ds_reads done
        gld16(lA0, gA + k0);
        gld16(lA1, gA + (size_t)64 * DIN + k0);
        gld16(lB0, gB + k0);
        gld16(lB1, gB + (size_t)64 * DIN + k0);
        __syncthreads();                       // vmcnt(0) drained before barrier

        bf16x8_t af[4], bfv[4];
#pragma unroll
        for (int i = 0; i < 4; ++i)
            af[i] = *reinterpret_cast<const bf16x8_t*>(&As[wm * 64 + i * 16 + r16][g * 8]);
#pragma unroll
        for (int j = 0; j < 4; ++j)
            bfv[j] = *reinterpret_cast<const bf16x8_t*>(&Bs[wn * 64 + j * 16 + r16][g * 8]);
#pragma unroll
        for (int i = 0; i < 4; ++i)
#pragma unroll
            for (int j = 0; j < 4; ++j)
                acc[i][j] = __builtin_amdgcn_mfma_f32_16x16x32_bf16(af[i], bfv[j], acc[i][j], 0, 0, 0);
    }

    // epilogue: +bias, scale (Q only), bf16, scatter to [b,h,s,d]
#pragma unroll
    for (int j = 0; j < 4; ++j) {
        int e = n0 + wn * 64 + j * 16 + r16;      // C col = lane&15
        float bv_ = bias[e];
        int h = e >> 6, d = e & 63;
#pragma unroll
        for (int i = 0; i < 4; ++i) {
#pragma unroll
            for (int r = 0; r < 4; ++r) {
                int m = m0 + wm * 64 + i * 16 + g * 4 + r;   // C row = 4g + reg
                int b = m >> 11, s = m & 2047;
                float val = (acc[i][j][r] + bv_) * qs;
                outp[(((size_t)(b * HNO + h)) * SLEN + s) * HSZ + d] = f2bf(val);
            }
        }
    }
}

// ---------------------------------------------------------------------------
// Stage 2: causal flash attention. Block = 4 waves, BQ=64 (16 q/wave),
// KVBLK=64. S^T = K·Q^T (lane owns one q-column -> lane-local softmax),
// O^T = V^T·P^T (coalesced output stores along s). Reg->LDS async staging.
// grid = 2048 (1D, swizzled), block = 256.
// ---------------------------------------------------------------------------
__global__ __launch_bounds__(256) void attn_kernel(
    const u16* __restrict__ qb, const u16* __restrict__ kb,
    const u16* __restrict__ vb, float* __restrict__ out)
{
    __shared__ __attribute__((aligned(16))) u16 Ks[64][72];     // K tile [kv][d]
    __shared__ __attribute__((aligned(16))) u16 Vt[64][72];     // V^T tile [d][kv]
    __shared__ __attribute__((aligned(16))) u16 P2[4][16][72];  // per-wave P[q][kv]

    const int t    = threadIdx.x;
    const int wid  = t >> 6;
    const int lane = t & 63;
    const int g    = lane >> 4;
    const int r16  = lane & 15;

    const int w   = blockIdx.x;
    const int idx = w >> 3;
    const int bh  = (w & 7) * 8 + (idx & 7);   // 8 heads per XCD
    const int qt  = 31 - (idx >> 3);           // big causal blocks first
    const int q0  = qt * 64;
    const size_t base = (size_t)bh * (SLEN * HSZ);

    const int qi = q0 + wid * 16 + r16;
    bf16x8_t qf0 = *reinterpret_cast<const bf16x8_t*>(&qb[base + (size_t)qi * HSZ + g * 8]);
    bf16x8_t qf1 = *reinterpret_cast<const bf16x8_t*>(&qb[base + (size_t)qi * HSZ + 32 + g * 8]);

    const int krow = t >> 3, kc0 = (t & 7) * 8;
    const int vrp  = t & 31, vc0 = (t >> 5) * 8;

    f32x4_t o[4] = {};
    float mrow = -1e30f, lrow = 0.f;

    const int ntiles = qt + 1;

    uint4 kA = *reinterpret_cast<const uint4*>(&kb[base + (size_t)krow * HSZ + kc0]);
    uint4 kB = *reinterpret_cast<const uint4*>(&kb[base + (size_t)(krow + 32) * HSZ + kc0]);
    uint4 vA = *reinterpret_cast<const uint4*>(&vb[base + (size_t)(2 * vrp) * HSZ + vc0]);
    uint4 vB = *reinterpret_cast<const uint4*>(&vb[base + (size_t)(2 * vrp + 1) * HSZ + vc0]);

    for (int kt = 0; kt < ntiles; ++kt) {
        const int kv0 = kt * 64;
        __syncthreads();
        *reinterpret_cast<uint4*>(&Ks[krow][kc0])      = kA;
        *reinterpret_cast<uint4*>(&Ks[krow + 32][kc0]) = kB;
        {
            const u16* p0 = reinterpret_cast<const u16*>(&vA);
            const u16* p1 = reinterpret_cast<const u16*>(&vB);
#pragma unroll
            for (int j = 0; j < 8; ++j) {
                unsigned pk = (unsigned)p0[j] | ((unsigned)p1[j] << 16);
                *reinterpret_cast<unsigned*>(&Vt[vc0 + j][2 * vrp]) = pk;
            }
        }
        __syncthreads();

        if (kt + 1 < ntiles) {
            const size_t nb = base + (size_t)(kv0 + 64) * HSZ;
            kA = *reinterpret_cast<const uint4*>(&kb[nb + (size_t)krow * HSZ + kc0]);
            kB = *reinterpret_cast<const uint4*>(&kb[nb + (size_t)(krow + 32) * HSZ + kc0]);
            vA = *reinterpret_cast<const uint4*>(&vb[nb + (size_t)(2 * vrp) * HSZ + vc0]);
            vB = *reinterpret_cast<const uint4*>(&vb[nb + (size_t)(2 * vrp + 1) * HSZ + vc0]);
        }

        f32x4_t c_[4];
#pragma unroll
        for (int m = 0; m < 4; ++m) {
            bf16x8_t a0 = *reinterpret_cast<const bf16x8_t*>(&Ks[m * 16 + r16][g * 8]);
            bf16x8_t a1 = *reinterpret_cast<const bf16x8_t*>(&Ks[m * 16 + r16][32 + g * 8]);
            f32x4_t cc = {};
            cc = __builtin_amdgcn_mfma_f32_16x16x32_bf16(a0, qf0, cc, 0, 0, 0);
            cc = __builtin_amdgcn_mfma_f32_16x16x32_bf16(a1, qf1, cc, 0, 0, 0);
            c_[m] = cc;
        }

        float s[16];
        float tmax = -1e30f;
        if (kt == qt) {
#pragma unroll
            for (int m = 0; m < 4; ++m)
#pragma unroll
                for (int r = 0; r < 4; ++r) {
                    int kj = kv0 + m * 16 + g * 4 + r;
                    float v = (kj <= qi) ? c_[m][r] : -1e30f;
                    s[m * 4 + r] = v;
                    tmax = fmaxf(tmax, v);
                }
        } else {
#pragma unroll
            for (int m = 0; m < 4; ++m)
#pragma unroll
                for (int r = 0; r < 4; ++r) {
                    float v = c_[m][r];
                    s[m * 4 + r] = v;
                    tmax = fmaxf(tmax, v);
                }
        }
        tmax = fmaxf(tmax, __shfl_xor(tmax, 16));
        tmax = fmaxf(tmax, __shfl_xor(tmax, 32));

        if (!__all(tmax - mrow <= 8.0f)) {
            float mnew  = fmaxf(mrow, tmax);
            float alpha = __expf(mrow - mnew);
#pragma unroll
            for (int j = 0; j < 4; ++j) {
                o[j][0] *= alpha; o[j][1] *= alpha; o[j][2] *= alpha; o[j][3] *= alpha;
            }
            lrow *= alpha;
            mrow = mnew;
        }

        float p[16];
        float tsum = 0.f;
#pragma unroll
        for (int i = 0; i < 16; ++i) {
            p[i] = __expf(s[i] - mrow);
            tsum += p[i];
        }
        tsum += __shfl_xor(tsum, 16);
        tsum += __shfl_xor(tsum, 32);
        lrow += tsum;

#pragma unroll
        for (int m = 0; m < 4; ++m) {
            unsigned long long pk =
                (unsigned long long)f2bf(p[m * 4 + 0])         |
                ((unsigned long long)f2bf(p[m * 4 + 1]) << 16) |
                ((unsigned long long)f2bf(p[m * 4 + 2]) << 32) |
                ((unsigned long long)f2bf(p[m * 4 + 3]) << 48);
            *reinterpret_cast<unsigned long long*>(&P2[wid][r16][m * 16 + g * 4]) = pk;
        }

#pragma unroll
        for (int c = 0; c < 2; ++c) {
            bf16x8_t pf = *reinterpret_cast<const bf16x8_t*>(&P2[wid][r16][c * 32 + g * 8]);
#pragma unroll
            for (int j = 0; j < 4; ++j) {
                bf16x8_t vf = *reinterpret_cast<const bf16x8_t*>(&Vt[j * 16 + r16][c * 32 + g * 8]);
                o[j] = __builtin_amdgcn_mfma_f32_16x16x32_bf16(vf, pf, o[j], 0, 0, 0);
            }
        }
    }

    float rinv = 1.0f / lrow;
    const int b = bh >> 4, h = bh & 15;
    float* outb = out + (size_t)b * (SLEN * EMB) + (size_t)h * (HSZ * SLEN);
#pragma unroll
    for (int j = 0; j < 4; ++j) {
#pragma unroll
        for (int r = 0; r < 4; ++r) {
            int d = j * 16 + g * 4 + r;
            outb[(size_t)d * SLEN + qi] = o[j][r] * rinv;
        }
    }
}

// ---------------------------------------------------------------------------
extern "C" void kernel_launch(void* const* d_in, const int* in_sizes, int n_in,
                              void* d_out, int out_size, void* d_ws, size_t ws_size,
                              hipStream_t stream) {
    const float* x  = (const float*)d_in[0];
    const float* Wq = (const float*)d_in[1];
    const float* bq = (const float*)d_in[2];
    const float* Wk = (const float*)d_in[3];
    const float* bk = (const float*)d_in[4];
    const float* Wv = (const float*)d_in[5];
    const float* bv = (const float*)d_in[6];
    float* out = (float*)d_out;

    const size_t per = (size_t)BSZ * HNO * SLEN * HSZ;   // 8,388,608
    u16* qw = (u16*)d_ws;            // 48 MB of workspace
    u16* kw = qw + per;
    u16* vw = kw + per;

    // bf16 scratch lives in d_out (23.1 MB < 33.5 MB); the GEMM finishes
    // reading it before attn_kernel overwrites d_out (stream-ordered).
    u16* xb = (u16*)d_out;                       // 8192*1024 bf16 = 16.8 MB
    u16* wb = xb + (size_t)BSZ * SLEN * DIN;     // 3*1024*1024 bf16 = 6.3 MB

    cvt_bf16_kernel<<<dim3(256, 4), 256, 0, stream>>>(x, Wq, Wk, Wv, xb, wb);
    qkv_gemm_kernel<<<dim3(64, 8, 3), 256, 0, stream>>>(xb, wb, bq, bk, bv, qw, kw, vw);
    attn_kernel<<<2048, 256, 0, stream>>>(qw, kw, vw, out);
}

// Round 4
// 148.760 us; speedup vs baseline: 2.4167x; 1.0292x over previous
//
#include <hip/hip_runtime.h>

// MHA forward, MI355X gfx950.
// Sizes: B=4, S=2048, DIN=EMB=1024, H=16, D(head)=64.
// Stage 0: one-shot fp32->bf16 convert of x and Wq/Wk/Wv (memory-bound),
//          bf16 copies live in d_out (used as scratch; attn overwrites it).
// Stage 1: pure-bf16 QKV GEMM, m97 structure (128x128, BK=32,
//          global_load_lds width-16). Q pre-scaled by log2(e)/sqrt(64) so
//          attention scores land in log2 units (exp2 softmax).
// Stage 2: causal flash attention, KVBLK=64, reg->LDS async staging,
//          VALU-dieted softmax: v_exp_f32 direct, v_cvt_pk_bf16_f32 packing,
//          v_perm_b32 V-transpose, s_setprio around MFMA clusters.

#define BSZ 4
#define SLEN 2048
#define DIN 1024
#define EMB 1024
#define HNO 16
#define HSZ 64

typedef unsigned short u16;
typedef __bf16 bf16x8_t __attribute__((ext_vector_type(8)));
typedef float f32x4_t __attribute__((ext_vector_type(4)));

__device__ __forceinline__ u16 f2bf(float f) {
    unsigned u = __float_as_uint(f);
    u += 0x7FFFu + ((u >> 16) & 1u);   // RNE; inputs are finite
    return (u16)(u >> 16);
}

__device__ __forceinline__ float exp2_fast(float x) {     // v_exp_f32 = 2^x
    float r;
    asm("v_exp_f32 %0, %1" : "=v"(r) : "v"(x));
    return r;
}

__device__ __forceinline__ unsigned cvt_pk_bf16(float lo, float hi) {
    unsigned r;
    asm("v_cvt_pk_bf16_f32 %0, %1, %2" : "=v"(r) : "v"(lo), "v"(hi));
    return r;
}

__device__ __forceinline__ void gld16(void* lds, const void* g) {
    __builtin_amdgcn_global_load_lds(
        (const __attribute__((address_space(1))) void*)g,
        (__attribute__((address_space(3))) void*)lds, 16, 0, 0);
}

// ---------------------------------------------------------------------------
// Stage 0: fp32 -> bf16, vectorized (32B in / 16B out per lane per iter).
// blockIdx.y: 0 = x, 1..3 = Wq/Wk/Wv (into contiguous wb).
// ---------------------------------------------------------------------------
__global__ __launch_bounds__(256) void cvt_bf16_kernel(
    const float* __restrict__ x,  const float* __restrict__ wq,
    const float* __restrict__ wk, const float* __restrict__ wv,
    u16* __restrict__ xo, u16* __restrict__ wo)
{
    const int y = blockIdx.y;
    const float* src = (y == 0) ? x : (y == 1) ? wq : (y == 2) ? wk : wv;
    u16* dst = (y == 0) ? xo : wo + (size_t)(y - 1) * (EMB * DIN);
    const int n8 = (y == 0) ? (BSZ * SLEN * DIN / 8) : (EMB * DIN / 8);

    for (int i = blockIdx.x * 256 + threadIdx.x; i < n8; i += gridDim.x * 256) {
        float4 a = *reinterpret_cast<const float4*>(src + (size_t)i * 8);
        float4 b = *reinterpret_cast<const float4*>(src + (size_t)i * 8 + 4);
        union { u16 h[8]; uint4 u; } p;
        p.h[0] = f2bf(a.x); p.h[1] = f2bf(a.y); p.h[2] = f2bf(a.z); p.h[3] = f2bf(a.w);
        p.h[4] = f2bf(b.x); p.h[5] = f2bf(b.y); p.h[6] = f2bf(b.z); p.h[7] = f2bf(b.w);
        *reinterpret_cast<uint4*>(dst + (size_t)i * 8) = p.u;
    }
}

// ---------------------------------------------------------------------------
// Stage 1: Y = xb @ W^T + b, all bf16 inputs. m97 structure: 128x128 tile,
// BK=32, 4 waves (2x2), 4x4 16x16x32 frags/wave, global_load_lds staging.
// grid = (64 Mtiles, 8 Ntiles, 3 matrices), block = 256.
// ---------------------------------------------------------------------------
__global__ __launch_bounds__(256) void qkv_gemm_kernel(
    const u16* __restrict__ xb, const u16* __restrict__ wb,
    const float* __restrict__ bq, const float* __restrict__ bk,
    const float* __restrict__ bv,
    u16* __restrict__ qo, u16* __restrict__ ko, u16* __restrict__ vo)
{
    __shared__ __attribute__((aligned(16))) u16 As[128][32];  // linear: gld dest
    __shared__ __attribute__((aligned(16))) u16 Bs[128][32];

    const int t    = threadIdx.x;
    const int wid  = t >> 6;
    const int lane = t & 63;
    const int g    = lane >> 4;
    const int r16  = lane & 15;

    const int m0  = blockIdx.x * 128;
    const int n0  = blockIdx.y * 128;
    const int mat = blockIdx.z;

    const u16*   W    = wb + (size_t)mat * (EMB * DIN);
    const float* bias = (mat == 0) ? bq : (mat == 1) ? bk : bv;
    u16*         outp = (mat == 0) ? qo : (mat == 1) ? ko : vo;
    // Q carries 1/sqrt(64) * log2(e) so attention works in exp2 domain
    const float  qs   = (mat == 0) ? 0.125f * 1.44269504f : 1.0f;

    const int wm = wid >> 1, wn = wid & 1;

    const int srow = lane >> 2;
    const int scol = (lane & 3) * 8;
    const u16* gA = xb + (size_t)(m0 + wid * 16 + srow) * DIN + scol;
    const u16* gB = W  + (size_t)(n0 + wid * 16 + srow) * DIN + scol;
    u16* lA0 = &As[wid * 16][0];
    u16* lA1 = &As[64 + wid * 16][0];
    u16* lB0 = &Bs[wid * 16][0];
    u16* lB1 = &Bs[64 + wid * 16][0];

    f32x4_t acc[4][4] = {};

    for (int k0 = 0; k0 < DIN; k0 += 32) {
        __syncthreads();
        gld16(lA0, gA + k0);
        gld16(lA1, gA + (size_t)64 * DIN + k0);
        gld16(lB0, gB + k0);
        gld16(lB1, gB + (size_t)64 * DIN + k0);
        __syncthreads();

        bf16x8_t af[4], bfv[4];
#pragma unroll
        for (int i = 0; i < 4; ++i)
            af[i] = *reinterpret_cast<const bf16x8_t*>(&As[wm * 64 + i * 16 + r16][g * 8]);
#pragma unroll
        for (int j = 0; j < 4; ++j)
            bfv[j] = *reinterpret_cast<const bf16x8_t*>(&Bs[wn * 64 + j * 16 + r16][g * 8]);
#pragma unroll
        for (int i = 0; i < 4; ++i)
#pragma unroll
            for (int j = 0; j < 4; ++j)
                acc[i][j] = __builtin_amdgcn_mfma_f32_16x16x32_bf16(af[i], bfv[j], acc[i][j], 0, 0, 0);
    }

#pragma unroll
    for (int j = 0; j < 4; ++j) {
        int e = n0 + wn * 64 + j * 16 + r16;
        float bv_ = bias[e];
        int h = e >> 6, d = e & 63;
#pragma unroll
        for (int i = 0; i < 4; ++i) {
#pragma unroll
            for (int r = 0; r < 4; ++r) {
                int m = m0 + wm * 64 + i * 16 + g * 4 + r;
                int b = m >> 11, s = m & 2047;
                float val = (acc[i][j][r] + bv_) * qs;
                outp[(((size_t)(b * HNO + h)) * SLEN + s) * HSZ + d] = f2bf(val);
            }
        }
    }
}

// ---------------------------------------------------------------------------
// Stage 2: causal flash attention. Block = 4 waves, BQ=64 (16 q/wave),
// KVBLK=64. S^T = K·Q^T (lane owns one q-column -> lane-local softmax),
// O^T = V^T·P^T (coalesced output stores along s). Reg->LDS async staging.
// grid = 2048 (1D, swizzled), block = 256.
// ---------------------------------------------------------------------------
__global__ __launch_bounds__(256) void attn_kernel(
    const u16* __restrict__ qb, const u16* __restrict__ kb,
    const u16* __restrict__ vb, float* __restrict__ out)
{
    __shared__ __attribute__((aligned(16))) u16 Ks[64][72];     // K tile [kv][d]
    __shared__ __attribute__((aligned(16))) u16 Vt[64][72];     // V^T tile [d][kv]
    __shared__ __attribute__((aligned(16))) u16 P2[4][16][72];  // per-wave P[q][kv]

    const int t    = threadIdx.x;
    const int wid  = t >> 6;
    const int lane = t & 63;
    const int g    = lane >> 4;
    const int r16  = lane & 15;

    const int w   = blockIdx.x;
    const int idx = w >> 3;
    const int bh  = (w & 7) * 8 + (idx & 7);   // 8 heads per XCD
    const int qt  = 31 - (idx >> 3);           // big causal blocks first
    const int q0  = qt * 64;
    const size_t base = (size_t)bh * (SLEN * HSZ);

    const int qi = q0 + wid * 16 + r16;
    bf16x8_t qf0 = *reinterpret_cast<const bf16x8_t*>(&qb[base + (size_t)qi * HSZ + g * 8]);
    bf16x8_t qf1 = *reinterpret_cast<const bf16x8_t*>(&qb[base + (size_t)qi * HSZ + 32 + g * 8]);

    const int krow = t >> 3, kc0 = (t & 7) * 8;
    const int vrp  = t & 31, vc0 = (t >> 5) * 8;

    f32x4_t o[4] = {};
    float mrow = -1e30f, lrow = 0.f;            // mrow in log2 units

    const int ntiles = qt + 1;

    uint4 kA = *reinterpret_cast<const uint4*>(&kb[base + (size_t)krow * HSZ + kc0]);
    uint4 kB = *reinterpret_cast<const uint4*>(&kb[base + (size_t)(krow + 32) * HSZ + kc0]);
    uint4 vA = *reinterpret_cast<const uint4*>(&vb[base + (size_t)(2 * vrp) * HSZ + vc0]);
    uint4 vB = *reinterpret_cast<const uint4*>(&vb[base + (size_t)(2 * vrp + 1) * HSZ + vc0]);

    for (int kt = 0; kt < ntiles; ++kt) {
        const int kv0 = kt * 64;
        __syncthreads();
        *reinterpret_cast<uint4*>(&Ks[krow][kc0])      = kA;
        *reinterpret_cast<uint4*>(&Ks[krow + 32][kc0]) = kB;
        {   // V^T staging: v_perm packs (vA.h[j] | vB.h[j]<<16) in 1 op
            const unsigned* pa = reinterpret_cast<const unsigned*>(&vA);
            const unsigned* pb = reinterpret_cast<const unsigned*>(&vB);
#pragma unroll
            for (int j2 = 0; j2 < 4; ++j2) {
                unsigned lo = __builtin_amdgcn_perm(pb[j2], pa[j2], 0x05040100u);
                unsigned hi = __builtin_amdgcn_perm(pb[j2], pa[j2], 0x07060302u);
                *reinterpret_cast<unsigned*>(&Vt[vc0 + 2 * j2][2 * vrp])     = lo;
                *reinterpret_cast<unsigned*>(&Vt[vc0 + 2 * j2 + 1][2 * vrp]) = hi;
            }
        }
        __syncthreads();

        if (kt + 1 < ntiles) {
            const size_t nb = base + (size_t)(kv0 + 64) * HSZ;
            kA = *reinterpret_cast<const uint4*>(&kb[nb + (size_t)krow * HSZ + kc0]);
            kB = *reinterpret_cast<const uint4*>(&kb[nb + (size_t)(krow + 32) * HSZ + kc0]);
            vA = *reinterpret_cast<const uint4*>(&vb[nb + (size_t)(2 * vrp) * HSZ + vc0]);
            vB = *reinterpret_cast<const uint4*>(&vb[nb + (size_t)(2 * vrp + 1) * HSZ + vc0]);
        }

        // S^T = K·Q^T (scores already in log2 units via Q prescale)
        f32x4_t c_[4];
        __builtin_amdgcn_s_setprio(1);
#pragma unroll
        for (int m = 0; m < 4; ++m) {
            bf16x8_t a0 = *reinterpret_cast<const bf16x8_t*>(&Ks[m * 16 + r16][g * 8]);
            bf16x8_t a1 = *reinterpret_cast<const bf16x8_t*>(&Ks[m * 16 + r16][32 + g * 8]);
            f32x4_t cc = {};
            cc = __builtin_amdgcn_mfma_f32_16x16x32_bf16(a0, qf0, cc, 0, 0, 0);
            cc = __builtin_amdgcn_mfma_f32_16x16x32_bf16(a1, qf1, cc, 0, 0, 0);
            c_[m] = cc;
        }
        __builtin_amdgcn_s_setprio(0);

        float s[16];
        if (kt == qt) {
#pragma unroll
            for (int m = 0; m < 4; ++m)
#pragma unroll
                for (int r = 0; r < 4; ++r) {
                    int kj = kv0 + m * 16 + g * 4 + r;
                    s[m * 4 + r] = (kj <= qi) ? c_[m][r] : -1e30f;
                }
        } else {
#pragma unroll
            for (int m = 0; m < 4; ++m)
#pragma unroll
                for (int r = 0; r < 4; ++r)
                    s[m * 4 + r] = c_[m][r];
        }
        // balanced max tree
        float x0 = fmaxf(s[0], s[1]),   x1 = fmaxf(s[2], s[3]);
        float x2 = fmaxf(s[4], s[5]),   x3 = fmaxf(s[6], s[7]);
        float x4 = fmaxf(s[8], s[9]),   x5 = fmaxf(s[10], s[11]);
        float x6 = fmaxf(s[12], s[13]), x7 = fmaxf(s[14], s[15]);
        x0 = fmaxf(x0, x1); x2 = fmaxf(x2, x3); x4 = fmaxf(x4, x5); x6 = fmaxf(x6, x7);
        float tmax = fmaxf(fmaxf(x0, x2), fmaxf(x4, x6));
        tmax = fmaxf(tmax, __shfl_xor(tmax, 16));
        tmax = fmaxf(tmax, __shfl_xor(tmax, 32));

        if (!__all(tmax - mrow <= 8.0f)) {  // defer-max (log2 units: P <= 256)
            float mnew  = fmaxf(mrow, tmax);
            float alpha = exp2_fast(mrow - mnew);
#pragma unroll
            for (int j = 0; j < 4; ++j) {
                o[j][0] *= alpha; o[j][1] *= alpha; o[j][2] *= alpha; o[j][3] *= alpha;
            }
            lrow *= alpha;
            mrow = mnew;
        }

        float p[16];
#pragma unroll
        for (int i = 0; i < 16; ++i)
            p[i] = exp2_fast(s[i] - mrow);
        float y0 = (p[0] + p[1]) + (p[2] + p[3]);
        float y1 = (p[4] + p[5]) + (p[6] + p[7]);
        float y2 = (p[8] + p[9]) + (p[10] + p[11]);
        float y3 = (p[12] + p[13]) + (p[14] + p[15]);
        float tsum = (y0 + y1) + (y2 + y3);
        tsum += __shfl_xor(tsum, 16);
        tsum += __shfl_xor(tsum, 32);
        lrow += tsum;

        // P -> bf16 via v_cvt_pk, straight into per-wave LDS (b64 writes)
#pragma unroll
        for (int m = 0; m < 4; ++m) {
            uint2 pk;
            pk.x = cvt_pk_bf16(p[m * 4 + 0], p[m * 4 + 1]);
            pk.y = cvt_pk_bf16(p[m * 4 + 2], p[m * 4 + 3]);
            *reinterpret_cast<uint2*>(&P2[wid][r16][m * 16 + g * 4]) = pk;
        }

        // O^T += V^T·P^T
        __builtin_amdgcn_s_setprio(1);
#pragma unroll
        for (int c = 0; c < 2; ++c) {
            bf16x8_t pf = *reinterpret_cast<const bf16x8_t*>(&P2[wid][r16][c * 32 + g * 8]);
#pragma unroll
            for (int j = 0; j < 4; ++j) {
                bf16x8_t vf = *reinterpret_cast<const bf16x8_t*>(&Vt[j * 16 + r16][c * 32 + g * 8]);
                o[j] = __builtin_amdgcn_mfma_f32_16x16x32_bf16(vf, pf, o[j], 0, 0, 0);
            }
        }
        __builtin_amdgcn_s_setprio(0);
    }

    float rinv = 1.0f / lrow;
    const int b = bh >> 4, h = bh & 15;
    float* outb = out + (size_t)b * (SLEN * EMB) + (size_t)h * (HSZ * SLEN);
#pragma unroll
    for (int j = 0; j < 4; ++j) {
#pragma unroll
        for (int r = 0; r < 4; ++r) {
            int d = j * 16 + g * 4 + r;
            outb[(size_t)d * SLEN + qi] = o[j][r] * rinv;
        }
    }
}

// ---------------------------------------------------------------------------
extern "C" void kernel_launch(void* const* d_in, const int* in_sizes, int n_in,
                              void* d_out, int out_size, void* d_ws, size_t ws_size,
                              hipStream_t stream) {
    const float* x  = (const float*)d_in[0];
    const float* Wq = (const float*)d_in[1];
    const float* bq = (const float*)d_in[2];
    const float* Wk = (const float*)d_in[3];
    const float* bk = (const float*)d_in[4];
    const float* Wv = (const float*)d_in[5];
    const float* bv = (const float*)d_in[6];
    float* out = (float*)d_out;

    const size_t per = (size_t)BSZ * HNO * SLEN * HSZ;   // 8,388,608
    u16* qw = (u16*)d_ws;            // 48 MB of workspace
    u16* kw = qw + per;
    u16* vw = kw + per;

    // bf16 scratch lives in d_out (23.1 MB < 33.5 MB); the GEMM finishes
    // reading it before attn_kernel overwrites d_out (stream-ordered).
    u16* xb = (u16*)d_out;                       // 8192*1024 bf16 = 16.8 MB
    u16* wb = xb + (size_t)BSZ * SLEN * DIN;     // 3*1024*1024 bf16 = 6.3 MB

    cvt_bf16_kernel<<<dim3(256, 4), 256, 0, stream>>>(x, Wq, Wk, Wv, xb, wb);
    qkv_gemm_kernel<<<dim3(64, 8, 3), 256, 0, stream>>>(xb, wb, bq, bk, bv, qw, kw, vw);
    attn_kernel<<<2048, 256, 0, stream>>>(qw, kw, vw, out);
}

// Round 5
// 136.278 us; speedup vs baseline: 2.6381x; 1.0916x over previous
//
#include <hip/hip_runtime.h>

// MHA forward, MI355X gfx950.
// Sizes: B=4, S=2048, DIN=EMB=1024, H=16, D(head)=64.
// Stage 0: one-shot fp32->bf16 convert of x and Wq/Wk/Wv (memory-bound),
//          bf16 copies live in d_out (used as scratch; attn overwrites it).
// Stage 1: pure-bf16 QKV GEMM, m97 structure (128x128, BK=32,
//          global_load_lds width-16). Q pre-scaled by log2(e)/sqrt(64).
// Stage 2: causal flash attention, BQ=128 (8 waves), KVBLK=64.
//          K staged via global_load_lds with XOR-slot swizzle (linear LDS,
//          pre-swizzled global source); V reg-staged transpose (perm-packed);
//          lane-local softmax in exp2 domain; O^T stored coalesced along s.

#define BSZ 4
#define SLEN 2048
#define DIN 1024
#define EMB 1024
#define HNO 16
#define HSZ 64

typedef unsigned short u16;
typedef __bf16 bf16x8_t __attribute__((ext_vector_type(8)));
typedef float f32x4_t __attribute__((ext_vector_type(4)));

__device__ __forceinline__ u16 f2bf(float f) {
    unsigned u = __float_as_uint(f);
    u += 0x7FFFu + ((u >> 16) & 1u);   // RNE; inputs are finite
    return (u16)(u >> 16);
}

__device__ __forceinline__ float exp2_fast(float x) {     // v_exp_f32 = 2^x
    float r;
    asm("v_exp_f32 %0, %1" : "=v"(r) : "v"(x));
    return r;
}

__device__ __forceinline__ unsigned cvt_pk_bf16(float lo, float hi) {
    unsigned r;
    asm("v_cvt_pk_bf16_f32 %0, %1, %2" : "=v"(r) : "v"(lo), "v"(hi));
    return r;
}

__device__ __forceinline__ void gld16(void* lds, const void* g) {
    __builtin_amdgcn_global_load_lds(
        (const __attribute__((address_space(1))) void*)g,
        (__attribute__((address_space(3))) void*)lds, 16, 0, 0);
}

// ---------------------------------------------------------------------------
// Stage 0: fp32 -> bf16, vectorized (32B in / 16B out per lane per iter).
// ---------------------------------------------------------------------------
__global__ __launch_bounds__(256) void cvt_bf16_kernel(
    const float* __restrict__ x,  const float* __restrict__ wq,
    const float* __restrict__ wk, const float* __restrict__ wv,
    u16* __restrict__ xo, u16* __restrict__ wo)
{
    const int y = blockIdx.y;
    const float* src = (y == 0) ? x : (y == 1) ? wq : (y == 2) ? wk : wv;
    u16* dst = (y == 0) ? xo : wo + (size_t)(y - 1) * (EMB * DIN);
    const int n8 = (y == 0) ? (BSZ * SLEN * DIN / 8) : (EMB * DIN / 8);

    for (int i = blockIdx.x * 256 + threadIdx.x; i < n8; i += gridDim.x * 256) {
        float4 a = *reinterpret_cast<const float4*>(src + (size_t)i * 8);
        float4 b = *reinterpret_cast<const float4*>(src + (size_t)i * 8 + 4);
        union { u16 h[8]; uint4 u; } p;
        p.h[0] = f2bf(a.x); p.h[1] = f2bf(a.y); p.h[2] = f2bf(a.z); p.h[3] = f2bf(a.w);
        p.h[4] = f2bf(b.x); p.h[5] = f2bf(b.y); p.h[6] = f2bf(b.z); p.h[7] = f2bf(b.w);
        *reinterpret_cast<uint4*>(dst + (size_t)i * 8) = p.u;
    }
}

// ---------------------------------------------------------------------------
// Stage 1: Y = xb @ W^T + b, all bf16 inputs. m97 structure.
// grid = (64, 8, 3), block = 256.
// ---------------------------------------------------------------------------
__global__ __launch_bounds__(256) void qkv_gemm_kernel(
    const u16* __restrict__ xb, const u16* __restrict__ wb,
    const float* __restrict__ bq, const float* __restrict__ bk,
    const float* __restrict__ bv,
    u16* __restrict__ qo, u16* __restrict__ ko, u16* __restrict__ vo)
{
    __shared__ __attribute__((aligned(16))) u16 As[128][32];
    __shared__ __attribute__((aligned(16))) u16 Bs[128][32];

    const int t    = threadIdx.x;
    const int wid  = t >> 6;
    const int lane = t & 63;
    const int g    = lane >> 4;
    const int r16  = lane & 15;

    const int m0  = blockIdx.x * 128;
    const int n0  = blockIdx.y * 128;
    const int mat = blockIdx.z;

    const u16*   W    = wb + (size_t)mat * (EMB * DIN);
    const float* bias = (mat == 0) ? bq : (mat == 1) ? bk : bv;
    u16*         outp = (mat == 0) ? qo : (mat == 1) ? ko : vo;
    const float  qs   = (mat == 0) ? 0.125f * 1.44269504f : 1.0f;

    const int wm = wid >> 1, wn = wid & 1;

    const int srow = lane >> 2;
    const int scol = (lane & 3) * 8;
    const u16* gA = xb + (size_t)(m0 + wid * 16 + srow) * DIN + scol;
    const u16* gB = W  + (size_t)(n0 + wid * 16 + srow) * DIN + scol;
    u16* lA0 = &As[wid * 16][0];
    u16* lA1 = &As[64 + wid * 16][0];
    u16* lB0 = &Bs[wid * 16][0];
    u16* lB1 = &Bs[64 + wid * 16][0];

    f32x4_t acc[4][4] = {};

    for (int k0 = 0; k0 < DIN; k0 += 32) {
        __syncthreads();
        gld16(lA0, gA + k0);
        gld16(lA1, gA + (size_t)64 * DIN + k0);
        gld16(lB0, gB + k0);
        gld16(lB1, gB + (size_t)64 * DIN + k0);
        __syncthreads();

        bf16x8_t af[4], bfv[4];
#pragma unroll
        for (int i = 0; i < 4; ++i)
            af[i] = *reinterpret_cast<const bf16x8_t*>(&As[wm * 64 + i * 16 + r16][g * 8]);
#pragma unroll
        for (int j = 0; j < 4; ++j)
            bfv[j] = *reinterpret_cast<const bf16x8_t*>(&Bs[wn * 64 + j * 16 + r16][g * 8]);
#pragma unroll
        for (int i = 0; i < 4; ++i)
#pragma unroll
            for (int j = 0; j < 4; ++j)
                acc[i][j] = __builtin_amdgcn_mfma_f32_16x16x32_bf16(af[i], bfv[j], acc[i][j], 0, 0, 0);
    }

#pragma unroll
    for (int j = 0; j < 4; ++j) {
        int e = n0 + wn * 64 + j * 16 + r16;
        float bv_ = bias[e];
        int h = e >> 6, d = e & 63;
#pragma unroll
        for (int i = 0; i < 4; ++i) {
#pragma unroll
            for (int r = 0; r < 4; ++r) {
                int m = m0 + wm * 64 + i * 16 + g * 4 + r;
                int b = m >> 11, s = m & 2047;
                float val = (acc[i][j][r] + bv_) * qs;
                outp[(((size_t)(b * HNO + h)) * SLEN + s) * HSZ + d] = f2bf(val);
            }
        }
    }
}

// ---------------------------------------------------------------------------
// Stage 2: causal flash attention. Block = 8 waves (512 thr), BQ=128
// (16 q/wave), KVBLK=64. S^T = K·Q^T (lane-local softmax), O^T = V^T·P^T.
// K tile: global_load_lds, linear [64][64], XOR-slot swizzle on source+read.
// grid = 1024 (1D, swizzled), block = 512.
// ---------------------------------------------------------------------------
__global__ __launch_bounds__(512, 6) void attn_kernel(
    const u16* __restrict__ qb, const u16* __restrict__ kb,
    const u16* __restrict__ vb, float* __restrict__ out)
{
    __shared__ __attribute__((aligned(16))) u16 Ks[64][64];     // linear: gld dest
    __shared__ __attribute__((aligned(16))) u16 Vt[64][72];     // V^T tile [d][kv]
    __shared__ __attribute__((aligned(16))) u16 P2[8][16][72];  // per-wave P[q][kv]

    const int t    = threadIdx.x;
    const int wid  = t >> 6;
    const int lane = t & 63;
    const int g    = lane >> 4;
    const int r16  = lane & 15;

    const int w   = blockIdx.x;
    const int idx = w >> 3;
    const int bh  = (w & 7) * 8 + (idx & 7);   // 8 heads per XCD
    const int qt  = 15 - (idx >> 3);           // big causal blocks first
    const int q0  = qt * 128;
    const size_t base = (size_t)bh * (SLEN * HSZ);

    const int qi = q0 + wid * 16 + r16;        // this lane's q column
    bf16x8_t qf0 = *reinterpret_cast<const bf16x8_t*>(&qb[base + (size_t)qi * HSZ + g * 8]);
    bf16x8_t qf1 = *reinterpret_cast<const bf16x8_t*>(&qb[base + (size_t)qi * HSZ + 32 + g * 8]);

    // K staging map (gld16): wave wid stages rows 8*wid..8*wid+7; lane l ->
    // row 8*wid + (l>>3), LDS slot l&7. Source chunk = slot ^ (row&7).
    const int krl   = lane >> 3;                       // row within wave slab
    const int kchunk = ((lane & 7) ^ krl) * 8;         // swizzled source col (u16)
    const int krow_g = wid * 8 + krl;                  // row within tile
    u16* kdst = &Ks[wid * 8][0];                       // wave-uniform dest

    // V staging map: a = row-pair 0..31, c4 = 4-col group 0..15
    const int va  = t & 31;
    const int vc4 = (t >> 5) * 4;

    // slot offset for QK A-frag reads: chunk g of row r16 -> slot g^(r16&7)
    const int ksl = ((g ^ (r16 & 7)) * 8);

    f32x4_t o[4] = {};
    float mrow = -1e30f, lrow = 0.f;            // log2 units

    const int ntiles = 2 * qt + 2;
    const int qw0 = q0 + wid * 16;              // wave's min q
    const int qmax_wave = qw0 + 15;

    // preload V tile 0 into regs
    uint2 v0 = *reinterpret_cast<const uint2*>(&vb[base + (size_t)(2 * va) * HSZ + vc4]);
    uint2 v1 = *reinterpret_cast<const uint2*>(&vb[base + (size_t)(2 * va + 1) * HSZ + vc4]);

    for (int kt = 0; kt < ntiles; ++kt) {
        const int kv0 = kt * 64;
        __syncthreads();                         // prev tile's readers done
        // K: async global->LDS (whole 8KB tile in one issue)
        gld16(kdst, &kb[base + (size_t)(kv0 + krow_g) * HSZ + kchunk]);
        // V: regs -> LDS transposed (perm-packed, conflict-free)
        {
            const unsigned* pa = reinterpret_cast<const unsigned*>(&v0);
            const unsigned* pb = reinterpret_cast<const unsigned*>(&v1);
#pragma unroll
            for (int j2 = 0; j2 < 2; ++j2) {
                unsigned lo = __builtin_amdgcn_perm(pb[j2], pa[j2], 0x05040100u);
                unsigned hi = __builtin_amdgcn_perm(pb[j2], pa[j2], 0x07060302u);
                *reinterpret_cast<unsigned*>(&Vt[vc4 + 2 * j2][2 * va])     = lo;
                *reinterpret_cast<unsigned*>(&Vt[vc4 + 2 * j2 + 1][2 * va]) = hi;
            }
        }
        __syncthreads();                         // vmcnt(0)+lgkm(0) drained

        if (kt + 1 < ntiles) {                   // prefetch next V (overlaps compute)
            const size_t nb = base + (size_t)(kv0 + 64) * HSZ;
            v0 = *reinterpret_cast<const uint2*>(&vb[nb + (size_t)(2 * va) * HSZ + vc4]);
            v1 = *reinterpret_cast<const uint2*>(&vb[nb + (size_t)(2 * va + 1) * HSZ + vc4]);
        }

        if (kv0 > qmax_wave) continue;           // fully-masked tile for this wave

        // S^T = K·Q^T (scores in log2 units via Q prescale)
        f32x4_t c_[4];
        __builtin_amdgcn_s_setprio(1);
#pragma unroll
        for (int m = 0; m < 4; ++m) {
            bf16x8_t a0 = *reinterpret_cast<const bf16x8_t*>(&Ks[m * 16 + r16][ksl]);
            bf16x8_t a1 = *reinterpret_cast<const bf16x8_t*>(&Ks[m * 16 + r16][ksl ^ 32]);
            f32x4_t cc = {};
            cc = __builtin_amdgcn_mfma_f32_16x16x32_bf16(a0, qf0, cc, 0, 0, 0);
            cc = __builtin_amdgcn_mfma_f32_16x16x32_bf16(a1, qf1, cc, 0, 0, 0);
            c_[m] = cc;
        }
        __builtin_amdgcn_s_setprio(0);

        float s[16];
        if (kv0 + 63 > qw0) {                    // diagonal-ish: per-lane mask
#pragma unroll
            for (int m = 0; m < 4; ++m)
#pragma unroll
                for (int r = 0; r < 4; ++r) {
                    int kj = kv0 + m * 16 + g * 4 + r;
                    s[m * 4 + r] = (kj <= qi) ? c_[m][r] : -1e30f;
                }
        } else {
#pragma unroll
            for (int m = 0; m < 4; ++m)
#pragma unroll
                for (int r = 0; r < 4; ++r)
                    s[m * 4 + r] = c_[m][r];
        }
        // balanced max tree
        float x0 = fmaxf(s[0], s[1]),   x1 = fmaxf(s[2], s[3]);
        float x2 = fmaxf(s[4], s[5]),   x3 = fmaxf(s[6], s[7]);
        float x4 = fmaxf(s[8], s[9]),   x5 = fmaxf(s[10], s[11]);
        float x6 = fmaxf(s[12], s[13]), x7 = fmaxf(s[14], s[15]);
        x0 = fmaxf(x0, x1); x2 = fmaxf(x2, x3); x4 = fmaxf(x4, x5); x6 = fmaxf(x6, x7);
        float tmax = fmaxf(fmaxf(x0, x2), fmaxf(x4, x6));
        tmax = fmaxf(tmax, __shfl_xor(tmax, 16));
        tmax = fmaxf(tmax, __shfl_xor(tmax, 32));

        if (!__all(tmax - mrow <= 8.0f)) {       // defer-max (P <= 2^8)
            float mnew  = fmaxf(mrow, tmax);
            float alpha = exp2_fast(mrow - mnew);
#pragma unroll
            for (int j = 0; j < 4; ++j) {
                o[j][0] *= alpha; o[j][1] *= alpha; o[j][2] *= alpha; o[j][3] *= alpha;
            }
            lrow *= alpha;
            mrow = mnew;
        }

#pragma unroll
        for (int i = 0; i < 16; ++i)
            s[i] = exp2_fast(s[i] - mrow);       // p in place
        float y0 = (s[0] + s[1]) + (s[2] + s[3]);
        float y1 = (s[4] + s[5]) + (s[6] + s[7]);
        float y2 = (s[8] + s[9]) + (s[10] + s[11]);
        float y3 = (s[12] + s[13]) + (s[14] + s[15]);
        float tsum = (y0 + y1) + (y2 + y3);
        tsum += __shfl_xor(tsum, 16);
        tsum += __shfl_xor(tsum, 32);
        lrow += tsum;

        // P -> bf16 via v_cvt_pk, into per-wave LDS (b64 writes)
#pragma unroll
        for (int m = 0; m < 4; ++m) {
            uint2 pk;
            pk.x = cvt_pk_bf16(s[m * 4 + 0], s[m * 4 + 1]);
            pk.y = cvt_pk_bf16(s[m * 4 + 2], s[m * 4 + 3]);
            *reinterpret_cast<uint2*>(&P2[wid][r16][m * 16 + g * 4]) = pk;
        }

        // O^T += V^T·P^T
        __builtin_amdgcn_s_setprio(1);
#pragma unroll
        for (int c = 0; c < 2; ++c) {
            bf16x8_t pf = *reinterpret_cast<const bf16x8_t*>(&P2[wid][r16][c * 32 + g * 8]);
#pragma unroll
            for (int j = 0; j < 4; ++j) {
                bf16x8_t vf = *reinterpret_cast<const bf16x8_t*>(&Vt[j * 16 + r16][c * 32 + g * 8]);
                o[j] = __builtin_amdgcn_mfma_f32_16x16x32_bf16(vf, pf, o[j], 0, 0, 0);
            }
        }
        __builtin_amdgcn_s_setprio(0);
    }

    // normalize + store: out[b][h*64*2048 + d*2048 + s], coalesced along s
    float rinv = 1.0f / lrow;
    const int b = bh >> 4, h = bh & 15;
    float* outb = out + (size_t)b * (SLEN * EMB) + (size_t)h * (HSZ * SLEN);
#pragma unroll
    for (int j = 0; j < 4; ++j) {
#pragma unroll
        for (int r = 0; r < 4; ++r) {
            int d = j * 16 + g * 4 + r;
            outb[(size_t)d * SLEN + qi] = o[j][r] * rinv;
        }
    }
}

// ---------------------------------------------------------------------------
extern "C" void kernel_launch(void* const* d_in, const int* in_sizes, int n_in,
                              void* d_out, int out_size, void* d_ws, size_t ws_size,
                              hipStream_t stream) {
    const float* x  = (const float*)d_in[0];
    const float* Wq = (const float*)d_in[1];
    const float* bq = (const float*)d_in[2];
    const float* Wk = (const float*)d_in[3];
    const float* bk = (const float*)d_in[4];
    const float* Wv = (const float*)d_in[5];
    const float* bv = (const float*)d_in[6];
    float* out = (float*)d_out;

    const size_t per = (size_t)BSZ * HNO * SLEN * HSZ;   // 8,388,608
    u16* qw = (u16*)d_ws;            // 48 MB of workspace
    u16* kw = qw + per;
    u16* vw = kw + per;

    // bf16 scratch lives in d_out (23.1 MB < 33.5 MB); the GEMM finishes
    // reading it before attn_kernel overwrites d_out (stream-ordered).
    u16* xb = (u16*)d_out;                       // 16.8 MB
    u16* wb = xb + (size_t)BSZ * SLEN * DIN;     // 6.3 MB

    cvt_bf16_kernel<<<dim3(256, 4), 256, 0, stream>>>(x, Wq, Wk, Wv, xb, wb);
    qkv_gemm_kernel<<<dim3(64, 8, 3), 256, 0, stream>>>(xb, wb, bq, bk, bv, qw, kw, vw);
    attn_kernel<<<1024, 512, 0, stream>>>(qw, kw, vw, out);
}